// Round 2
// baseline (1999.028 us; speedup 1.0000x reference)
//
#include <hip/hip_runtime.h>

typedef unsigned short u16;
typedef float f32x4 __attribute__((ext_vector_type(4)));
typedef __bf16 bf16v8 __attribute__((ext_vector_type(8)));
typedef u16 u16x4 __attribute__((ext_vector_type(4)));

__device__ __forceinline__ u16 f2bf(float f) {
  union { float f; unsigned int u; } v; v.f = f;
  unsigned int x = v.u;
  x += 0x7fffu + ((x >> 16) & 1u);   // round-to-nearest-even
  return (u16)(x >> 16);
}

__device__ __forceinline__ int refl(int i, int n) {
  i = (i < 0) ? -i : i;
  return (i >= n) ? (2 * n - 2 - i) : i;
}

__device__ __forceinline__ void gload_lds16(const void* g, void* l) {
  __builtin_amdgcn_global_load_lds(
      (const __attribute__((address_space(1))) void*)g,
      (__attribute__((address_space(3))) void*)l, 16, 0, 0);
}

// ---------------------------------------------------------------------------
// GEMM: C[m,n] = sum_k A[m,k] * Bt[n,k]   (A,Bt bf16 row-major, lda=ldb=K)
// 128x128 tile, BK=32, 4 waves, mfma_f32_16x16x32_bf16.
// Depth-2 pipeline: 3 LDS buffers, counted vmcnt(4), raw s_barrier (1/iter).
// Chunk swizzle: 16B chunk c of row r lives at LDS chunk c ^ ((r>>1)&3),
// applied to the GLOBAL source address (gload_lds dest stays linear) and to
// the ds_read address (both-sides involution).
// XCD swizzle: bijective m204 remap of the linearized block index.
// ---------------------------------------------------------------------------
enum { EPI_BF16_BIAS = 0, EPI_F32 = 1, EPI_BF16 = 2, EPI_F32_RES = 3, EPI_GELU = 4 };

template <int EPI>
__global__ __launch_bounds__(256, 2) void gemm_bt(
    const u16* __restrict__ A, const u16* __restrict__ Bt, void* __restrict__ Cp,
    const float* __restrict__ bias, int K, int Nld, long sA, long sB, long sC)
{
  __shared__ __align__(16) u16 As[3][128 * 32];
  __shared__ __align__(16) u16 Bs[3][128 * 32];

  const int t = threadIdx.x;

  // ---- bijective XCD-aware block remap (T1 / m204) ----
  const int gx = gridDim.x, gy = gridDim.y;
  const int nwg = gx * gy * (int)gridDim.z;
  const int orig = ((int)blockIdx.z * gy + (int)blockIdx.y) * gx + (int)blockIdx.x;
  const int q = nwg >> 3, r = nwg & 7;
  const int xcd = orig & 7, loc = orig >> 3;
  const int swz = (xcd < r ? xcd * (q + 1) : r * (q + 1) + (xcd - r) * q) + loc;
  const int gxy = gx * gy;
  const int bz = swz / gxy;
  const int rem = swz - bz * gxy;
  const int by = rem / gx, bx = rem - by * gx;

  const int m0 = by * 128, n0 = bx * 128;
  const u16* Ab = A + (long)bz * sA + (long)m0 * K;
  const u16* Bb = Bt + (long)bz * sB + (long)n0 * K;

  // staging: thread t loads 16B chunks t and t+256 of each 128x32 tile
  const int row  = t >> 2;
  const int scol = (((t & 3) ^ ((t >> 3) & 3)) << 3);  // swizzled source col (elems)
  const u16* Ag0 = Ab + (long)row * K + scol;
  const u16* Ag1 = Ab + (long)(row + 64) * K + scol;
  const u16* Bg0 = Bb + (long)row * K + scol;
  const u16* Bg1 = Bb + (long)(row + 64) * K + scol;

  auto STAGE = [&](int b, int k0) {
    gload_lds16(Ag0 + k0, &As[b][t * 8]);
    gload_lds16(Ag1 + k0, &As[b][(t + 256) * 8]);
    gload_lds16(Bg0 + k0, &Bs[b][t * 8]);
    gload_lds16(Bg1 + k0, &Bs[b][(t + 256) * 8]);
  };

  const int w = t >> 6, lane = t & 63;
  const int wm = (w >> 1) << 6, wn = (w & 1) << 6;
  const int lr = lane & 15, lc = lane >> 4;

  f32x4 acc[4][4];
  const f32x4 vzero = {0.f, 0.f, 0.f, 0.f};
#pragma unroll
  for (int i = 0; i < 4; i++)
#pragma unroll
    for (int j = 0; j < 4; j++) acc[i][j] = vzero;

  STAGE(0, 0);
  STAGE(1, 32);
  int cur = 0;

  for (int k0 = 0; k0 < K; k0 += 32) {
    // wait for tile `cur` (oldest 4 loads); keep next tile in flight
    if (k0 + 32 < K) asm volatile("s_waitcnt vmcnt(4)" ::: "memory");
    else             asm volatile("s_waitcnt vmcnt(0)" ::: "memory");
    __builtin_amdgcn_s_barrier();

    // prefetch tile cur+2 (readers of its buffer all passed the barrier)
    if (k0 + 64 < K) {
      int nb = cur + 2; if (nb >= 3) nb -= 3;
      STAGE(nb, k0 + 64);
    }

    const u16* Ac = &As[cur][0];
    const u16* Bc = &Bs[cur][0];
    bf16v8 av[4], bv[4];
#pragma unroll
    for (int i = 0; i < 4; i++) {
      const int ra = wm + i * 16 + lr;
      av[i] = *(const bf16v8*)&Ac[ra * 32 + ((lc ^ ((ra >> 1) & 3)) << 3)];
      const int rb = wn + i * 16 + lr;
      bv[i] = *(const bf16v8*)&Bc[rb * 32 + ((lc ^ ((rb >> 1) & 3)) << 3)];
    }
#pragma unroll
    for (int mi = 0; mi < 4; mi++)
#pragma unroll
      for (int ni = 0; ni < 4; ni++)
        acc[mi][ni] = __builtin_amdgcn_mfma_f32_16x16x32_bf16(av[mi], bv[ni], acc[mi][ni], 0, 0, 0);

    cur = (cur == 2) ? 0 : cur + 1;
  }

  // epilogue: C/D layout col = lane&15, row = (lane>>4)*4 + j
#pragma unroll
  for (int mi = 0; mi < 4; mi++) {
    const int r0 = m0 + wm + mi * 16 + lc * 4;
#pragma unroll
    for (int ni = 0; ni < 4; ni++) {
      const int col = n0 + wn + ni * 16 + lr;
      float bvv = 0.f;
      if constexpr (EPI == EPI_BF16_BIAS || EPI == EPI_F32_RES || EPI == EPI_GELU)
        bvv = bias[col];
#pragma unroll
      for (int j = 0; j < 4; j++) {
        const long idx = (long)(r0 + j) * Nld + col;
        float val = acc[mi][ni][j] + bvv;
        if constexpr (EPI == EPI_F32) {
          ((float*)Cp + (long)bz * sC)[idx] = val;
        } else if constexpr (EPI == EPI_F32_RES) {
          float* Cf = (float*)Cp + (long)bz * sC;
          Cf[idx] += val;
        } else if constexpr (EPI == EPI_GELU) {
          u16* Cb = (u16*)Cp + (long)bz * sC;
          const float gv = 0.5f * val * (1.f + erff(val * 0.70710678118654752440f));
          Cb[idx] = f2bf(gv);
        } else {
          u16* Cb = (u16*)Cp + (long)bz * sC;
          Cb[idx] = f2bf(val);
        }
      }
    }
  }
}

// ---------------------------------------------------------------------------
// LayerNorm: f32 [row,1024] -> bf16, one block per row
// ---------------------------------------------------------------------------
__global__ __launch_bounds__(256) void ln_kernel(const float* __restrict__ X,
    const float* __restrict__ g, const float* __restrict__ be, u16* __restrict__ Y)
{
  const long row = blockIdx.x;
  const int t = threadIdx.x;
  const float* xr = X + row * 1024;
  f32x4 v = *(const f32x4*)&xr[t * 4];
  float s = v[0] + v[1] + v[2] + v[3];
  float q = v[0]*v[0] + v[1]*v[1] + v[2]*v[2] + v[3]*v[3];
#pragma unroll
  for (int off = 32; off; off >>= 1) { s += __shfl_xor(s, off); q += __shfl_xor(q, off); }
  __shared__ float red[8];
  if ((t & 63) == 0) { red[t >> 6] = s; red[4 + (t >> 6)] = q; }
  __syncthreads();
  s = red[0] + red[1] + red[2] + red[3];
  q = red[4] + red[5] + red[6] + red[7];
  const float mean = s * (1.f / 1024.f);
  const float rstd = rsqrtf(q * (1.f / 1024.f) - mean * mean + 1e-5f);
  f32x4 gv = *(const f32x4*)&g[t * 4];
  f32x4 bv = *(const f32x4*)&be[t * 4];
  u16x4 o;
#pragma unroll
  for (int i = 0; i < 4; i++) o[i] = f2bf((v[i] - mean) * rstd * gv[i] + bv[i]);
  *(u16x4*)&Y[row * 1024 + t * 4] = o;
}

// ---------------------------------------------------------------------------
// Patch (reflect-pad + unfold) -> f32 x buffer; pad rows zeroed
// ---------------------------------------------------------------------------
__global__ __launch_bounds__(256) void patch_kernel(const float* __restrict__ img,
    float* __restrict__ X, int shift)
{
  const int n = blockIdx.x, b = blockIdx.y, t = threadIdx.x;
  float* xr = X + ((long)b * 1152 + n) * 1024;
  if (n >= 1089) {
    const f32x4 z = {0.f, 0.f, 0.f, 0.f};
    *(f32x4*)&xr[t * 4] = z;
    return;
  }
  const int p = shift * 2;
  const int ph = n / 33, pw = n - ph * 33;
  const int d0 = t * 4;
  const int c = d0 >> 6, kh = (d0 >> 3) & 7, kw0 = d0 & 7;
  const int hh = refl(ph * 8 + kh - p, 256);
  const float* src = img + ((long)(b * 16 + c) * 256 + hh) * 256;
  f32x4 v;
#pragma unroll
  for (int i = 0; i < 4; i++) v[i] = src[refl(pw * 8 + kw0 + i - p, 256)];
  *(f32x4*)&xr[d0] = v;
}

// ---------------------------------------------------------------------------
// Patch + LayerNorm fused -> bf16 (for K and V inputs)
// ---------------------------------------------------------------------------
__global__ __launch_bounds__(256) void patch_ln_kernel(const float* __restrict__ img,
    const float* __restrict__ g, const float* __restrict__ be, u16* __restrict__ Y, int shift)
{
  const int n = blockIdx.x, b = blockIdx.y, t = threadIdx.x;
  u16* yr = Y + ((long)b * 1152 + n) * 1024;
  if (n >= 1089) {
    const u16x4 z = {0, 0, 0, 0};
    *(u16x4*)&yr[t * 4] = z;
    return;
  }
  const int p = shift * 2;
  const int ph = n / 33, pw = n - ph * 33;
  const int d0 = t * 4;
  const int c = d0 >> 6, kh = (d0 >> 3) & 7, kw0 = d0 & 7;
  const int hh = refl(ph * 8 + kh - p, 256);
  const float* src = img + ((long)(b * 16 + c) * 256 + hh) * 256;
  float v[4];
#pragma unroll
  for (int i = 0; i < 4; i++) v[i] = src[refl(pw * 8 + kw0 + i - p, 256)];
  float s = v[0] + v[1] + v[2] + v[3];
  float q = v[0]*v[0] + v[1]*v[1] + v[2]*v[2] + v[3]*v[3];
#pragma unroll
  for (int off = 32; off; off >>= 1) { s += __shfl_xor(s, off); q += __shfl_xor(q, off); }
  __shared__ float red[8];
  if ((t & 63) == 0) { red[t >> 6] = s; red[4 + (t >> 6)] = q; }
  __syncthreads();
  s = red[0] + red[1] + red[2] + red[3];
  q = red[4] + red[5] + red[6] + red[7];
  const float mean = s * (1.f / 1024.f);
  const float rstd = rsqrtf(q * (1.f / 1024.f) - mean * mean + 1e-5f);
  u16x4 o;
#pragma unroll
  for (int i = 0; i < 4; i++) o[i] = f2bf((v[i] - mean) * rstd * g[d0 + i] + be[d0 + i]);
  *(u16x4*)&yr[d0] = o;
}

// ---------------------------------------------------------------------------
// Row softmax with masking (valid cols < 1089), scale 1/32, bf16 out
// ---------------------------------------------------------------------------
__global__ __launch_bounds__(256) void softmax_kernel(const float* __restrict__ L,
    u16* __restrict__ P)
{
  const int r = blockIdx.x, b = blockIdx.y, t = threadIdx.x;
  const float* Lr = L + ((long)b * 1152 + r) * 1152;
  u16* Pr = P + ((long)b * 1152 + r) * 1152;
  float v[5];
  float mx = -1e30f;
#pragma unroll
  for (int i = 0; i < 5; i++) {
    const int j = t + i * 256;
    v[i] = (j < 1089) ? Lr[j] * 0.03125f : -1e30f;
    mx = fmaxf(mx, v[i]);
  }
#pragma unroll
  for (int off = 32; off; off >>= 1) mx = fmaxf(mx, __shfl_xor(mx, off));
  __shared__ float sm[4];
  if ((t & 63) == 0) sm[t >> 6] = mx;
  __syncthreads();
  mx = fmaxf(fmaxf(sm[0], sm[1]), fmaxf(sm[2], sm[3]));
  float p[5];
  float s = 0.f;
#pragma unroll
  for (int i = 0; i < 5; i++) {
    const int j = t + i * 256;
    p[i] = (j < 1089) ? __expf(v[i] - mx) : 0.f;
    s += p[i];
  }
#pragma unroll
  for (int off = 32; off; off >>= 1) s += __shfl_xor(s, off);
  __shared__ float ss[4];
  if ((t & 63) == 0) ss[t >> 6] = s;
  __syncthreads();
  const float inv = 1.f / (ss[0] + ss[1] + ss[2] + ss[3]);
#pragma unroll
  for (int i = 0; i < 5; i++) {
    const int j = t + i * 256;
    if (j < 1152) Pr[j] = f2bf(p[i] * inv);
  }
}

// ---------------------------------------------------------------------------
// Transposes
// ---------------------------------------------------------------------------
__global__ __launch_bounds__(256) void vtrans_kernel(const u16* __restrict__ V,
    u16* __restrict__ Vt)
{
  __shared__ u16 tile[32][33];
  const int b = blockIdx.z;
  const int d0 = blockIdx.x * 32, m0 = blockIdx.y * 32;
  const int tx = threadIdx.x & 31, ty = threadIdx.x >> 5;
  const u16* Vb = V + (long)b * 1152 * 3072;
  u16* Vtb = Vt + (long)b * 3072 * 1152;
#pragma unroll
  for (int i = 0; i < 4; i++)
    tile[ty + 8 * i][tx] = Vb[(long)(m0 + ty + 8 * i) * 3072 + d0 + tx];
  __syncthreads();
#pragma unroll
  for (int i = 0; i < 4; i++)
    Vtb[(long)(d0 + ty + 8 * i) * 1152 + m0 + tx] = tile[tx][ty + 8 * i];
}

__global__ __launch_bounds__(256) void wtrans_kernel(const float* __restrict__ W,
    u16* __restrict__ Wt, int K, int N)
{
  __shared__ float tile[32][33];
  const int n0 = blockIdx.x * 32, k0 = blockIdx.y * 32;
  const int tx = threadIdx.x & 31, ty = threadIdx.x >> 5;
#pragma unroll
  for (int i = 0; i < 4; i++)
    tile[ty + 8 * i][tx] = W[(long)(k0 + ty + 8 * i) * N + n0 + tx];
  __syncthreads();
#pragma unroll
  for (int i = 0; i < 4; i++)
    Wt[(long)(n0 + ty + 8 * i) * K + k0 + tx] = f2bf(tile[tx][ty + 8 * i]);
}

// ---------------------------------------------------------------------------
// Unpatch (inverse unfold + crop) -> f32 output
// ---------------------------------------------------------------------------
__global__ __launch_bounds__(256) void unpatch_kernel(const float* __restrict__ X,
    float* __restrict__ out)
{
  const int idx = blockIdx.x * 256 + threadIdx.x;  // one per 4 floats
  const int w = (idx & 63) * 4;
  const int h = (idx >> 6) & 255;
  const int c = (idx >> 14) & 15;
  const int b = idx >> 18;
  const int ph = h >> 3, kh = h & 7, pw = w >> 3, kw = w & 7;
  const long row = (long)b * 1152 + ph * 33 + pw;
  const int d = c * 64 + kh * 8 + kw;
  const f32x4 v = *(const f32x4*)&X[row * 1024 + d];
  *(f32x4*)&out[((long)(b * 16 + c) * 256 + h) * 256 + w] = v;
}

// ---------------------------------------------------------------------------
extern "C" void kernel_launch(void* const* d_in, const int* in_sizes, int n_in,
                              void* d_out, int out_size, void* d_ws, size_t ws_size,
                              hipStream_t stream)
{
  (void)in_sizes; (void)n_in; (void)out_size; (void)ws_size;
  const float* dr_img = (const float*)d_in[0];
  const float* dr_ref = (const float*)d_in[1];
  const float* cl_ref = (const float*)d_in[2];
  const float* ln_g = (const float*)d_in[3];
  const float* ln_be = (const float*)d_in[4];
  const float* Wq = (const float*)d_in[5];
  const float* bq = (const float*)d_in[6];
  const float* Wk = (const float*)d_in[7];
  const float* bk = (const float*)d_in[8];
  const float* Wv = (const float*)d_in[9];
  const float* bv = (const float*)d_in[10];
  const float* Wo = (const float*)d_in[11];
  const float* bo = (const float*)d_in[12];
  const float* ffg = (const float*)d_in[13];
  const float* ffb = (const float*)d_in[14];
  const float* W1 = (const float*)d_in[15];
  const float* b1 = (const float*)d_in[16];
  const float* W2 = (const float*)d_in[17];
  const float* b2 = (const float*)d_in[18];

  char* ws = (char*)d_ws;
  size_t off = 0;
  auto alloc = [&](size_t bytes) -> void* {
    void* pp = ws + off;
    off += (bytes + 255) & ~(size_t)255;
    return pp;
  };
  float* x   = (float*)alloc((size_t)4608 * 1024 * 4);
  u16* x_ln  = (u16*)alloc((size_t)4608 * 1024 * 2);
  u16* k_ln  = (u16*)alloc((size_t)4608 * 1024 * 2);  // aliased: FF hidden
  u16* v_ln  = (u16*)alloc((size_t)4608 * 1024 * 2);
  u16* qp    = (u16*)alloc((size_t)4608 * 3072 * 2);  // aliased: attn_out
  u16* kp    = (u16*)alloc((size_t)4608 * 3072 * 2);  // aliased: vp_t
  u16* vp    = (u16*)alloc((size_t)4608 * 3072 * 2);
  float* lgt = (float*)alloc((size_t)4 * 1152 * 1152 * 4);
  u16* P     = (u16*)alloc((size_t)4 * 1152 * 1152 * 2);
  u16* Wq_t  = (u16*)alloc((size_t)3072 * 1024 * 2);
  u16* Wk_t  = (u16*)alloc((size_t)3072 * 1024 * 2);
  u16* Wv_t  = (u16*)alloc((size_t)3072 * 1024 * 2);
  u16* Wo_t  = (u16*)alloc((size_t)1024 * 3072 * 2);
  u16* W1_t  = (u16*)alloc((size_t)1024 * 1024 * 2);
  u16* W2_t  = (u16*)alloc((size_t)1024 * 1024 * 2);

  wtrans_kernel<<<dim3(96, 32), 256, 0, stream>>>(Wq, Wq_t, 1024, 3072);
  wtrans_kernel<<<dim3(96, 32), 256, 0, stream>>>(Wk, Wk_t, 1024, 3072);
  wtrans_kernel<<<dim3(96, 32), 256, 0, stream>>>(Wv, Wv_t, 1024, 3072);
  wtrans_kernel<<<dim3(32, 96), 256, 0, stream>>>(Wo, Wo_t, 3072, 1024);
  wtrans_kernel<<<dim3(32, 32), 256, 0, stream>>>(W1, W1_t, 1024, 1024);
  wtrans_kernel<<<dim3(32, 32), 256, 0, stream>>>(W2, W2_t, 1024, 1024);

  patch_kernel<<<dim3(1152, 4), 256, 0, stream>>>(dr_img, x, 0);

  const long sQ = (long)1152 * 3072, sL = (long)1152 * 1152;

  for (int shift = 0; shift < 4; shift++) {
    ln_kernel<<<4608, 256, 0, stream>>>(x, ln_g, ln_be, x_ln);
    patch_ln_kernel<<<dim3(1152, 4), 256, 0, stream>>>(dr_ref, ln_g, ln_be, k_ln, shift);
    patch_ln_kernel<<<dim3(1152, 4), 256, 0, stream>>>(cl_ref, ln_g, ln_be, v_ln, shift);

    gemm_bt<EPI_BF16_BIAS><<<dim3(24, 36, 1), 256, 0, stream>>>(x_ln, Wq_t, qp, bq, 1024, 3072, 0, 0, 0);
    gemm_bt<EPI_BF16_BIAS><<<dim3(24, 36, 1), 256, 0, stream>>>(k_ln, Wk_t, kp, bk, 1024, 3072, 0, 0, 0);
    gemm_bt<EPI_BF16_BIAS><<<dim3(24, 36, 1), 256, 0, stream>>>(v_ln, Wv_t, vp, bv, 1024, 3072, 0, 0, 0);

    gemm_bt<EPI_F32><<<dim3(9, 9, 4), 256, 0, stream>>>(qp, kp, lgt, nullptr, 3072, 1152, sQ, sQ, sL);
    softmax_kernel<<<dim3(1152, 4), 256, 0, stream>>>(lgt, P);
    vtrans_kernel<<<dim3(96, 36, 4), 256, 0, stream>>>(vp, kp);  // vp_t -> kp buffer
    gemm_bt<EPI_BF16><<<dim3(24, 9, 4), 256, 0, stream>>>(P, kp, qp, nullptr, 1152, 3072, sL, sQ, sQ);
    gemm_bt<EPI_F32_RES><<<dim3(8, 36, 1), 256, 0, stream>>>(qp, Wo_t, x, bo, 3072, 1024, 0, 0, 0);

    ln_kernel<<<4608, 256, 0, stream>>>(x, ffg, ffb, x_ln);
    gemm_bt<EPI_GELU><<<dim3(8, 36, 1), 256, 0, stream>>>(x_ln, W1_t, k_ln, b1, 1024, 1024, 0, 0, 0);
    gemm_bt<EPI_F32_RES><<<dim3(8, 36, 1), 256, 0, stream>>>(k_ln, W2_t, x, b2, 1024, 1024, 0, 0, 0);
  }

  unpatch_kernel<<<4096, 256, 0, stream>>>(x, (float*)d_out);
}

// Round 3
// 1533.302 us; speedup vs baseline: 1.3037x; 1.3037x over previous
//
#include <hip/hip_runtime.h>

typedef unsigned short u16;
typedef float f32x4 __attribute__((ext_vector_type(4)));
typedef __bf16 bf16v8 __attribute__((ext_vector_type(8)));
typedef u16 u16x4 __attribute__((ext_vector_type(4)));

#define WAITV(n) asm volatile("s_waitcnt vmcnt(" #n ")" ::: "memory")
#define TOPBAR() asm volatile("s_barrier" ::: "memory")
#define ENDBAR() asm volatile("s_waitcnt lgkmcnt(0)\n\ts_barrier" ::: "memory")

__device__ __forceinline__ u16 f2bf(float f) {
  union { float f; unsigned int u; } v; v.f = f;
  unsigned int x = v.u;
  x += 0x7fffu + ((x >> 16) & 1u);   // round-to-nearest-even
  return (u16)(x >> 16);
}

__device__ __forceinline__ int refl(int i, int n) {
  i = (i < 0) ? -i : i;
  return (i >= n) ? (2 * n - 2 - i) : i;
}

__device__ __forceinline__ void gload_lds16(const void* g, void* l) {
  __builtin_amdgcn_global_load_lds(
      (const __attribute__((address_space(1))) void*)g,
      (__attribute__((address_space(3))) void*)l, 16, 0, 0);
}

enum { EPI_BF16_BIAS = 0, EPI_F32 = 1, EPI_BF16 = 2, EPI_F32_RES = 3, EPI_GELU = 4 };

// XCD-aware bijective block remap (m204). Returns linearized swizzled id.
__device__ __forceinline__ void xcd_remap(int& bx, int& by, int& bz) {
  const int gx = gridDim.x, gy = gridDim.y;
  const int nwg = gx * gy * (int)gridDim.z;
  const int orig = ((int)blockIdx.z * gy + (int)blockIdx.y) * gx + (int)blockIdx.x;
  const int q = nwg >> 3, r = nwg & 7;
  const int xcd = orig & 7, loc = orig >> 3;
  const int swz = (xcd < r ? xcd * (q + 1) : r * (q + 1) + (xcd - r) * q) + loc;
  const int gxy = gx * gy;
  bz = swz / gxy;
  const int rem = swz - bz * gxy;
  by = rem / gx; bx = rem - by * gx;
}

// ---------------------------------------------------------------------------
// gemm256: C[m,n] = sum_k A[m,k]*Bt[n,k].  256x256 tile, BK=64, 512 thr/8 waves.
// Double-buffered K-tiles, counted vmcnt(8), XOR swizzle ((row&7)<<4).
// LDS: dynamic 128KB  (As[2][256*64] | Bs[2][256*64] bf16)
// ---------------------------------------------------------------------------
template <int EPI>
__global__ __launch_bounds__(512, 2) void gemm256(
    const u16* __restrict__ A, const u16* __restrict__ Bt, void* __restrict__ Cp,
    const float* __restrict__ bias, int K, int Nld, long sA, long sB, long sC, long sBias)
{
  extern __shared__ __align__(16) u16 smem[];
  u16* As = smem;            // 2 * 16384
  u16* Bs = smem + 32768;    // 2 * 16384

  const int t = threadIdx.x;
  int bx, by, bz; xcd_remap(bx, by, bz);
  const int m0 = by * 256, n0 = bx * 256;

  const long Kb = (long)K * 2;
  const int sc = ((t & 7) * 16) ^ (((t >> 3) & 7) << 4);  // swizzled src byte-col
  const char* Ag = (const char*)(A + (long)bz * sA + (long)m0 * K) + (long)(t >> 3) * Kb + sc;
  const char* Bg = (const char*)(Bt + (long)bz * sB + (long)n0 * K) + (long)(t >> 3) * Kb + sc;

  auto STAGE = [&](int d, int kt) {
    const long ko = (long)kt * 128;
#pragma unroll
    for (int i = 0; i < 4; i++)
      gload_lds16(Ag + (long)i * 64 * Kb + ko, &As[d * 16384 + i * 4096 + t * 8]);
#pragma unroll
    for (int i = 0; i < 4; i++)
      gload_lds16(Bg + (long)i * 64 * Kb + ko, &Bs[d * 16384 + i * 4096 + t * 8]);
  };

  const int w = t >> 6, lane = t & 63;
  const int wm = (w >> 2) * 128, wn = (w & 3) * 64;   // 2M x 4N waves
  const int lr = lane & 15, hi = lane >> 4;
  const int cx = (lr & 7) << 4;                        // read-side XOR (bytes)

  f32x4 acc[8][4];
  const f32x4 vzero = {0.f, 0.f, 0.f, 0.f};
#pragma unroll
  for (int i = 0; i < 8; i++)
#pragma unroll
    for (int j = 0; j < 4; j++) acc[i][j] = vzero;

  const int NT = K >> 6;
  STAGE(0, 0);
  STAGE(1, 1);

  for (int kt = 0; kt < NT; kt++) {
    const int d = kt & 1;
    if (kt + 1 < NT) { WAITV(8); } else { WAITV(0); }
    TOPBAR();

    const u16* Ad = &As[d * 16384];
    const u16* Bd = &Bs[d * 16384];
#pragma unroll
    for (int ks = 0; ks < 2; ks++) {
      bf16v8 a8[8], b8[4];
      const int cb = ks * 64;  // byte col base of this k-sub
#pragma unroll
      for (int mi = 0; mi < 8; mi++)
        a8[mi] = *(const bf16v8*)&Ad[(wm + mi * 16 + lr) * 64 + (((cb + hi * 16) ^ cx) >> 1)];
#pragma unroll
      for (int ni = 0; ni < 4; ni++)
        b8[ni] = *(const bf16v8*)&Bd[(wn + ni * 16 + lr) * 64 + (((cb + hi * 16) ^ cx) >> 1)];
      __builtin_amdgcn_s_setprio(1);
#pragma unroll
      for (int mi = 0; mi < 8; mi++)
#pragma unroll
        for (int ni = 0; ni < 4; ni++)
          acc[mi][ni] = __builtin_amdgcn_mfma_f32_16x16x32_bf16(a8[mi], b8[ni], acc[mi][ni], 0, 0, 0);
      __builtin_amdgcn_s_setprio(0);
    }
    ENDBAR();
    if (kt + 2 < NT) STAGE(d, kt + 2);
  }

  // epilogue: col = lane&15, row = hi*4 + j  within each 16x16 fragment
#pragma unroll
  for (int mi = 0; mi < 8; mi++) {
    const int r0 = m0 + wm + mi * 16 + hi * 4;
#pragma unroll
    for (int ni = 0; ni < 4; ni++) {
      const int col = n0 + wn + ni * 16 + lr;
      float bvv = 0.f;
      if constexpr (EPI == EPI_BF16_BIAS) bvv = bias[bz * sBias + col];
#pragma unroll
      for (int j = 0; j < 4; j++) {
        const long idx = (long)(r0 + j) * Nld + col;
        const float val = acc[mi][ni][j] + bvv;
        if constexpr (EPI == EPI_BF16_BIAS || EPI == EPI_BF16) {
          ((u16*)Cp + (long)bz * sC)[idx] = f2bf(val);
        } else {
          ((float*)Cp + (long)bz * sC)[idx] = val;
        }
      }
    }
  }
}

// ---------------------------------------------------------------------------
// gemm128: same skeleton, 128x128 tile, BK=64, 256 thr/4 waves, 64KB LDS.
// ---------------------------------------------------------------------------
template <int EPI>
__global__ __launch_bounds__(256, 2) void gemm128(
    const u16* __restrict__ A, const u16* __restrict__ Bt, void* __restrict__ Cp,
    const float* __restrict__ bias, int K, int Nld, long sA, long sB, long sC)
{
  extern __shared__ __align__(16) u16 smem[];
  u16* As = smem;            // 2 * 8192
  u16* Bs = smem + 16384;    // 2 * 8192

  const int t = threadIdx.x;
  int bx, by, bz; xcd_remap(bx, by, bz);
  const int m0 = by * 128, n0 = bx * 128;

  const long Kb = (long)K * 2;
  const int sc = ((t & 7) * 16) ^ (((t >> 3) & 7) << 4);
  const char* Ag = (const char*)(A + (long)bz * sA + (long)m0 * K) + (long)(t >> 3) * Kb + sc;
  const char* Bg = (const char*)(Bt + (long)bz * sB + (long)n0 * K) + (long)(t >> 3) * Kb + sc;

  auto STAGE = [&](int d, int kt) {
    const long ko = (long)kt * 128;
#pragma unroll
    for (int i = 0; i < 4; i++)
      gload_lds16(Ag + (long)i * 32 * Kb + ko, &As[d * 8192 + i * 2048 + t * 8]);
#pragma unroll
    for (int i = 0; i < 4; i++)
      gload_lds16(Bg + (long)i * 32 * Kb + ko, &Bs[d * 8192 + i * 2048 + t * 8]);
  };

  const int w = t >> 6, lane = t & 63;
  const int wm = (w >> 1) * 64, wn = (w & 1) * 64;    // 2M x 2N waves
  const int lr = lane & 15, hi = lane >> 4;
  const int cx = (lr & 7) << 4;

  f32x4 acc[4][4];
  const f32x4 vzero = {0.f, 0.f, 0.f, 0.f};
#pragma unroll
  for (int i = 0; i < 4; i++)
#pragma unroll
    for (int j = 0; j < 4; j++) acc[i][j] = vzero;

  const int NT = K >> 6;
  STAGE(0, 0);
  STAGE(1, 1);

  for (int kt = 0; kt < NT; kt++) {
    const int d = kt & 1;
    if (kt + 1 < NT) { WAITV(8); } else { WAITV(0); }
    TOPBAR();

    const u16* Ad = &As[d * 8192];
    const u16* Bd = &Bs[d * 8192];
#pragma unroll
    for (int ks = 0; ks < 2; ks++) {
      bf16v8 a8[4], b8[4];
      const int cb = ks * 64;
#pragma unroll
      for (int mi = 0; mi < 4; mi++)
        a8[mi] = *(const bf16v8*)&Ad[(wm + mi * 16 + lr) * 64 + (((cb + hi * 16) ^ cx) >> 1)];
#pragma unroll
      for (int ni = 0; ni < 4; ni++)
        b8[ni] = *(const bf16v8*)&Bd[(wn + ni * 16 + lr) * 64 + (((cb + hi * 16) ^ cx) >> 1)];
      __builtin_amdgcn_s_setprio(1);
#pragma unroll
      for (int mi = 0; mi < 4; mi++)
#pragma unroll
        for (int ni = 0; ni < 4; ni++)
          acc[mi][ni] = __builtin_amdgcn_mfma_f32_16x16x32_bf16(a8[mi], b8[ni], acc[mi][ni], 0, 0, 0);
      __builtin_amdgcn_s_setprio(0);
    }
    ENDBAR();
    if (kt + 2 < NT) STAGE(d, kt + 2);
  }

#pragma unroll
  for (int mi = 0; mi < 4; mi++) {
    const int r0 = m0 + wm + mi * 16 + hi * 4;
#pragma unroll
    for (int ni = 0; ni < 4; ni++) {
      const int col = n0 + wn + ni * 16 + lr;
      float bvv = 0.f;
      if constexpr (EPI == EPI_F32_RES || EPI == EPI_GELU) bvv = bias[col];
#pragma unroll
      for (int j = 0; j < 4; j++) {
        const long idx = (long)(r0 + j) * Nld + col;
        const float val = acc[mi][ni][j] + bvv;
        if constexpr (EPI == EPI_F32) {
          ((float*)Cp + (long)bz * sC)[idx] = val;
        } else if constexpr (EPI == EPI_F32_RES) {
          ((float*)Cp)[idx] += val;
        } else if constexpr (EPI == EPI_GELU) {
          const float gv = 0.5f * val * (1.f + erff(val * 0.70710678118654752440f));
          ((u16*)Cp)[idx] = f2bf(gv);
        } else {
          ((u16*)Cp)[idx] = f2bf(val);
        }
      }
    }
  }
}

// ---------------------------------------------------------------------------
// LayerNorm: f32 [row,1024] -> bf16
// ---------------------------------------------------------------------------
__global__ __launch_bounds__(256) void ln_kernel(const float* __restrict__ X,
    const float* __restrict__ g, const float* __restrict__ be, u16* __restrict__ Y)
{
  const long row = blockIdx.x;
  const int t = threadIdx.x;
  const float* xr = X + row * 1024;
  f32x4 v = *(const f32x4*)&xr[t * 4];
  float s = v[0] + v[1] + v[2] + v[3];
  float q = v[0]*v[0] + v[1]*v[1] + v[2]*v[2] + v[3]*v[3];
#pragma unroll
  for (int off = 32; off; off >>= 1) { s += __shfl_xor(s, off); q += __shfl_xor(q, off); }
  __shared__ float red[8];
  if ((t & 63) == 0) { red[t >> 6] = s; red[4 + (t >> 6)] = q; }
  __syncthreads();
  s = red[0] + red[1] + red[2] + red[3];
  q = red[4] + red[5] + red[6] + red[7];
  const float mean = s * (1.f / 1024.f);
  const float rstd = rsqrtf(q * (1.f / 1024.f) - mean * mean + 1e-5f);
  f32x4 gv = *(const f32x4*)&g[t * 4];
  f32x4 bv = *(const f32x4*)&be[t * 4];
  u16x4 o;
#pragma unroll
  for (int i = 0; i < 4; i++) o[i] = f2bf((v[i] - mean) * rstd * gv[i] + bv[i]);
  *(u16x4*)&Y[row * 1024 + t * 4] = o;
}

// ---------------------------------------------------------------------------
// Patch (reflect-pad + unfold) -> f32 x buffer; pad rows zeroed. rows=1280/b
// ---------------------------------------------------------------------------
__global__ __launch_bounds__(256) void patch_kernel(const float* __restrict__ img,
    float* __restrict__ X, int shift)
{
  const int n = blockIdx.x, b = blockIdx.y, t = threadIdx.x;
  float* xr = X + ((long)b * 1280 + n) * 1024;
  if (n >= 1089) {
    const f32x4 z = {0.f, 0.f, 0.f, 0.f};
    *(f32x4*)&xr[t * 4] = z;
    return;
  }
  const int p = shift * 2;
  const int ph = n / 33, pw = n - ph * 33;
  const int d0 = t * 4;
  const int c = d0 >> 6, kh = (d0 >> 3) & 7, kw0 = d0 & 7;
  const int hh = refl(ph * 8 + kh - p, 256);
  const float* src = img + ((long)(b * 16 + c) * 256 + hh) * 256;
  f32x4 v;
#pragma unroll
  for (int i = 0; i < 4; i++) v[i] = src[refl(pw * 8 + kw0 + i - p, 256)];
  *(f32x4*)&xr[d0] = v;
}

// ---------------------------------------------------------------------------
// Patch + LayerNorm fused -> bf16 (K and V inputs)
// ---------------------------------------------------------------------------
__global__ __launch_bounds__(256) void patch_ln_kernel(const float* __restrict__ img,
    const float* __restrict__ g, const float* __restrict__ be, u16* __restrict__ Y, int shift)
{
  const int n = blockIdx.x, b = blockIdx.y, t = threadIdx.x;
  u16* yr = Y + ((long)b * 1280 + n) * 1024;
  if (n >= 1089) {
    const u16x4 z = {0, 0, 0, 0};
    *(u16x4*)&yr[t * 4] = z;
    return;
  }
  const int p = shift * 2;
  const int ph = n / 33, pw = n - ph * 33;
  const int d0 = t * 4;
  const int c = d0 >> 6, kh = (d0 >> 3) & 7, kw0 = d0 & 7;
  const int hh = refl(ph * 8 + kh - p, 256);
  const float* src = img + ((long)(b * 16 + c) * 256 + hh) * 256;
  float v[4];
#pragma unroll
  for (int i = 0; i < 4; i++) v[i] = src[refl(pw * 8 + kw0 + i - p, 256)];
  float s = v[0] + v[1] + v[2] + v[3];
  float q = v[0]*v[0] + v[1]*v[1] + v[2]*v[2] + v[3]*v[3];
#pragma unroll
  for (int off = 32; off; off >>= 1) { s += __shfl_xor(s, off); q += __shfl_xor(q, off); }
  __shared__ float red[8];
  if ((t & 63) == 0) { red[t >> 6] = s; red[4 + (t >> 6)] = q; }
  __syncthreads();
  s = red[0] + red[1] + red[2] + red[3];
  q = red[4] + red[5] + red[6] + red[7];
  const float mean = s * (1.f / 1024.f);
  const float rstd = rsqrtf(q * (1.f / 1024.f) - mean * mean + 1e-5f);
  u16x4 o;
#pragma unroll
  for (int i = 0; i < 4; i++) o[i] = f2bf((v[i] - mean) * rstd * g[d0 + i] + be[d0 + i]);
  *(u16x4*)&yr[d0] = o;
}

// ---------------------------------------------------------------------------
// Row softmax with masking (valid cols < 1089), scale 1/32, bf16 out. 1280 cols
// ---------------------------------------------------------------------------
__global__ __launch_bounds__(256) void softmax_kernel(const float* __restrict__ L,
    u16* __restrict__ P)
{
  const int r = blockIdx.x, b = blockIdx.y, t = threadIdx.x;
  const float* Lr = L + ((long)b * 1280 + r) * 1280;
  u16* Pr = P + ((long)b * 1280 + r) * 1280;
  float v[5];
  float mx = -1e30f;
#pragma unroll
  for (int i = 0; i < 5; i++) {
    const int j = t + i * 256;
    v[i] = (j < 1089) ? Lr[j] * 0.03125f : -1e30f;
    mx = fmaxf(mx, v[i]);
  }
#pragma unroll
  for (int off = 32; off; off >>= 1) mx = fmaxf(mx, __shfl_xor(mx, off));
  __shared__ float sm[4];
  if ((t & 63) == 0) sm[t >> 6] = mx;
  __syncthreads();
  mx = fmaxf(fmaxf(sm[0], sm[1]), fmaxf(sm[2], sm[3]));
  float p[5];
  float s = 0.f;
#pragma unroll
  for (int i = 0; i < 5; i++) {
    const int j = t + i * 256;
    p[i] = (j < 1089) ? __expf(v[i] - mx) : 0.f;
    s += p[i];
  }
#pragma unroll
  for (int off = 32; off; off >>= 1) s += __shfl_xor(s, off);
  __shared__ float ss[4];
  if ((t & 63) == 0) ss[t >> 6] = s;
  __syncthreads();
  const float inv = 1.f / (ss[0] + ss[1] + ss[2] + ss[3]);
#pragma unroll
  for (int i = 0; i < 5; i++) Pr[t + i * 256] = f2bf(p[i] * inv);
}

// ---------------------------------------------------------------------------
// Transposes
// ---------------------------------------------------------------------------
__global__ __launch_bounds__(256) void vtrans_kernel(const u16* __restrict__ V,
    u16* __restrict__ Vt)
{
  __shared__ u16 tile[32][33];
  const int b = blockIdx.z;
  const int d0 = blockIdx.x * 32, m0 = blockIdx.y * 32;
  const int tx = threadIdx.x & 31, ty = threadIdx.x >> 5;
  const u16* Vb = V + (long)b * 1280 * 3072;
  u16* Vtb = Vt + (long)b * 3072 * 1280;
#pragma unroll
  for (int i = 0; i < 4; i++)
    tile[ty + 8 * i][tx] = Vb[(long)(m0 + ty + 8 * i) * 3072 + d0 + tx];
  __syncthreads();
#pragma unroll
  for (int i = 0; i < 4; i++)
    Vtb[(long)(d0 + ty + 8 * i) * 1280 + m0 + tx] = tile[tx][ty + 8 * i];
}

__global__ __launch_bounds__(256) void wtrans_kernel(const float* __restrict__ W,
    u16* __restrict__ Wt, int K, int N)
{
  __shared__ float tile[32][33];
  const int n0 = blockIdx.x * 32, k0 = blockIdx.y * 32;
  const int tx = threadIdx.x & 31, ty = threadIdx.x >> 5;
#pragma unroll
  for (int i = 0; i < 4; i++)
    tile[ty + 8 * i][tx] = W[(long)(k0 + ty + 8 * i) * N + n0 + tx];
  __syncthreads();
#pragma unroll
  for (int i = 0; i < 4; i++)
    Wt[(long)(n0 + ty + 8 * i) * K + k0 + tx] = f2bf(tile[tx][ty + 8 * i]);
}

__global__ __launch_bounds__(256) void catbias_kernel(const float* __restrict__ a,
    const float* __restrict__ b, const float* __restrict__ c, float* __restrict__ o)
{
  const int i = blockIdx.x * 256 + threadIdx.x;  // 3072
  o[i] = a[i]; o[3072 + i] = b[i]; o[6144 + i] = c[i];
}

// ---------------------------------------------------------------------------
// Unpatch (inverse unfold + crop) -> f32 output
// ---------------------------------------------------------------------------
__global__ __launch_bounds__(256) void unpatch_kernel(const float* __restrict__ X,
    float* __restrict__ out)
{
  const int idx = blockIdx.x * 256 + threadIdx.x;  // one per 4 floats
  const int w = (idx & 63) * 4;
  const int h = (idx >> 6) & 255;
  const int c = (idx >> 14) & 15;
  const int b = idx >> 18;
  const int ph = h >> 3, kh = h & 7, pw = w >> 3, kw = w & 7;
  const long row = (long)b * 1280 + ph * 33 + pw;
  const int d = c * 64 + kh * 8 + kw;
  const f32x4 v = *(const f32x4*)&X[row * 1024 + d];
  *(f32x4*)&out[((long)(b * 16 + c) * 256 + h) * 256 + w] = v;
}

// ---------------------------------------------------------------------------
extern "C" void kernel_launch(void* const* d_in, const int* in_sizes, int n_in,
                              void* d_out, int out_size, void* d_ws, size_t ws_size,
                              hipStream_t stream)
{
  (void)in_sizes; (void)n_in; (void)out_size; (void)ws_size;
  const float* dr_img = (const float*)d_in[0];
  const float* dr_ref = (const float*)d_in[1];
  const float* cl_ref = (const float*)d_in[2];
  const float* ln_g = (const float*)d_in[3];
  const float* ln_be = (const float*)d_in[4];
  const float* Wq = (const float*)d_in[5];
  const float* bq = (const float*)d_in[6];
  const float* Wk = (const float*)d_in[7];
  const float* bk = (const float*)d_in[8];
  const float* Wv = (const float*)d_in[9];
  const float* bv = (const float*)d_in[10];
  const float* Wo = (const float*)d_in[11];
  const float* bo = (const float*)d_in[12];
  const float* ffg = (const float*)d_in[13];
  const float* ffb = (const float*)d_in[14];
  const float* W1 = (const float*)d_in[15];
  const float* b1 = (const float*)d_in[16];
  const float* W2 = (const float*)d_in[17];
  const float* b2 = (const float*)d_in[18];

  const long R = 1280;                 // padded tokens per batch
  const long MR = 4 * R;               // 5120 total rows

  char* ws = (char*)d_ws;
  size_t off = 0;
  auto alloc = [&](size_t bytes) -> void* {
    void* pp = ws + off;
    off += (bytes + 255) & ~(size_t)255;
    return pp;
  };
  float* x    = (float*)alloc((size_t)MR * 1024 * 4);
  u16* xkv_ln = (u16*)alloc((size_t)3 * MR * 1024 * 2);  // slot1 aliased: FF hidden
  u16* qkv    = (u16*)alloc((size_t)3 * MR * 3072 * 2);  // q / k(=vpt) / v ; q also attn_out
  float* lgt  = (float*)alloc((size_t)4 * R * R * 4);
  u16* P      = (u16*)alloc((size_t)4 * R * R * 2);
  u16* Wqkv_t = (u16*)alloc((size_t)3 * 3072 * 1024 * 2);
  u16* Wo_t   = (u16*)alloc((size_t)1024 * 3072 * 2);
  u16* W1_t   = (u16*)alloc((size_t)1024 * 1024 * 2);
  u16* W2_t   = (u16*)alloc((size_t)1024 * 1024 * 2);
  float* bcat = (float*)alloc((size_t)3 * 3072 * 4);

  u16* x_ln = xkv_ln;
  u16* h    = xkv_ln + (size_t)MR * 1024;      // FF hidden aliases k_ln slot
  u16* qp   = qkv;
  u16* kp   = qkv + (size_t)MR * 3072;         // also V^T after vtrans
  u16* vp   = qkv + (size_t)2 * MR * 3072;

  wtrans_kernel<<<dim3(96, 32), 256, 0, stream>>>(Wq, Wqkv_t, 1024, 3072);
  wtrans_kernel<<<dim3(96, 32), 256, 0, stream>>>(Wk, Wqkv_t + (size_t)3072 * 1024, 1024, 3072);
  wtrans_kernel<<<dim3(96, 32), 256, 0, stream>>>(Wv, Wqkv_t + (size_t)2 * 3072 * 1024, 1024, 3072);
  wtrans_kernel<<<dim3(32, 96), 256, 0, stream>>>(Wo, Wo_t, 3072, 1024);
  wtrans_kernel<<<dim3(32, 32), 256, 0, stream>>>(W1, W1_t, 1024, 1024);
  wtrans_kernel<<<dim3(32, 32), 256, 0, stream>>>(W2, W2_t, 1024, 1024);
  catbias_kernel<<<12, 256, 0, stream>>>(bq, bk, bv, bcat);

  patch_kernel<<<dim3(1280, 4), 256, 0, stream>>>(dr_img, x, 0);

  const long sAp = (long)MR * 1024;        // proj A slot stride
  const long sBp = (long)3072 * 1024;      // proj W slot stride
  const long sCp = (long)MR * 3072;        // proj C slot stride
  const long sQb = R * 3072;               // per-batch stride in qp/kp/vp
  const long sLb = R * R;

  for (int shift = 0; shift < 4; shift++) {
    ln_kernel<<<(int)MR, 256, 0, stream>>>(x, ln_g, ln_be, x_ln);
    patch_ln_kernel<<<dim3(1280, 4), 256, 0, stream>>>(dr_ref, ln_g, ln_be, xkv_ln + sAp, shift);
    patch_ln_kernel<<<dim3(1280, 4), 256, 0, stream>>>(cl_ref, ln_g, ln_be, xkv_ln + 2 * sAp, shift);

    // Q/K/V projections, z-batched: [5120,1024] x [3072,1024]^T -> [5120,3072]
    gemm256<EPI_BF16_BIAS><<<dim3(12, 20, 3), 512, 131072, stream>>>(
        xkv_ln, Wqkv_t, qkv, bcat, 1024, 3072, sAp, sBp, sCp, 3072);

    // logits: per batch [1280,3072] x [1280,3072]^T -> [1280,1280] f32
    gemm128<EPI_F32><<<dim3(10, 10, 4), 256, 65536, stream>>>(
        qp, kp, lgt, nullptr, 3072, 1280, sQb, sQb, sLb);

    softmax_kernel<<<dim3(1280, 4), 256, 0, stream>>>(lgt, P);
    vtrans_kernel<<<dim3(96, 40, 4), 256, 0, stream>>>(vp, kp);  // vp^T into kp

    // PV: per batch [1280,1280] x [3072,1280]^T -> [1280,3072] bf16 (into qp)
    gemm256<EPI_BF16><<<dim3(12, 5, 4), 512, 131072, stream>>>(
        P, kp, qp, nullptr, 1280, 3072, sLb, (long)3072 * R, sQb, 0);

    // out-proj + residual: [5120,3072] x [1024,3072]^T -> += x
    gemm128<EPI_F32_RES><<<dim3(8, 40, 1), 256, 65536, stream>>>(
        qp, Wo_t, x, bo, 3072, 1024, 0, 0, 0);

    ln_kernel<<<(int)MR, 256, 0, stream>>>(x, ffg, ffb, x_ln);
    gemm128<EPI_GELU><<<dim3(8, 40, 1), 256, 65536, stream>>>(
        x_ln, W1_t, h, b1, 1024, 1024, 0, 0, 0);
    gemm128<EPI_F32_RES><<<dim3(8, 40, 1), 256, 65536, stream>>>(
        h, W2_t, x, b2, 1024, 1024, 0, 0, 0);
  }

  unpatch_kernel<<<4096, 256, 0, stream>>>(x, (float*)d_out);
}